// Round 10
// baseline (166.799 us; speedup 1.0000x reference)
//
#include <hip/hip_runtime.h>
#include <hip/hip_bf16.h>

typedef __attribute__((ext_vector_type(8))) short short8;
typedef __attribute__((ext_vector_type(4))) float f32x4;
typedef __attribute__((ext_vector_type(16))) float f32x16;
typedef __attribute__((ext_vector_type(4))) unsigned int u32x4;
typedef __attribute__((ext_vector_type(2))) unsigned int u32x2;
typedef __attribute__((ext_vector_type(2))) int i32x2;

#define N_ 2048
#define LOG2E 1.44269504088896f

__device__ __forceinline__ unsigned short f2bf(float f) {
  return __builtin_bit_cast(unsigned short, __float2bfloat16(f));
}
__device__ __forceinline__ float bf2f(unsigned short u) {
  return __builtin_bit_cast(float, ((unsigned int)u) << 16);
}
__device__ __forceinline__ unsigned int pack2(float lo, float hi) {
  return ((unsigned int)f2bf(hi) << 16) | (unsigned int)f2bf(lo);
}

// ---------------- prep: transpose-cast Wr/Wf  +  rk/rq projections ----------------
// grid 2560: blocks 0..511 = cast_wT (16x16x2); 512..2559 = projr (2048, 2 rows each)
// rk is pre-scaled by log2(e) so QK scores come out in exp2 domain.
__global__ __launch_bounds__(256) void k_prep(
    const float* __restrict__ Wr, const float* __restrict__ Wf,
    const float* __restrict__ rh, const float* __restrict__ Wrs,
    const float* __restrict__ Wrt,
    unsigned short* __restrict__ WrT, unsigned short* __restrict__ WfT,
    unsigned short* __restrict__ rk, unsigned short* __restrict__ rq) {
  __shared__ float t[32][33];
  const int bid = blockIdx.x;
  const int tid = threadIdx.x;
  if (bid < 512) {
    const int zz = bid >> 8, rem = bid & 255;
    const int kt = (rem & 15) * 32, ct = (rem >> 4) * 32;
    const float* W = zz ? Wf : Wr;
    unsigned short* WT = zz ? WfT : WrT;
    const int r = tid >> 3, c4 = (tid & 7) * 4;
    f32x4 v = *reinterpret_cast<const f32x4*>(&W[(kt + r) * 512 + ct + c4]);
#pragma unroll
    for (int j = 0; j < 4; ++j) t[r][c4 + j] = v[j];
    __syncthreads();
    u32x2 o;
    o[0] = pack2(t[c4][r], t[c4 + 1][r]);
    o[1] = pack2(t[c4 + 2][r], t[c4 + 3][r]);
    *reinterpret_cast<u32x2*>(&WT[(ct + r) * 512 + kt + c4]) = o;
  } else {
    const int pb = bid - 512;
    const int col = tid & 127;
    const int ro = tid >> 7;
    const int nf = pb * 2 + ro;  // 0..4095
    const f32x4* src = reinterpret_cast<const f32x4*>(&rh[nf * 16]);
    f32x4 rv[4] = {src[0], src[1], src[2], src[3]};
    float sk = 0.f, sq = 0.f;
#pragma unroll
    for (int k4 = 0; k4 < 4; ++k4)
#pragma unroll
      for (int j = 0; j < 4; ++j) {
        float v = rv[k4][j];
        int k = k4 * 4 + j;
        sk += v * Wrs[k * 128 + col];
        sq += v * Wrt[k * 128 + col];
      }
    int bb = nf >> 11, n = nf & 2047, hh = col >> 4, r = col & 15;
    int oidx = ((bb * 8 + hh) * N_ + n) * 16 + r;
    rk[oidx] = f2bf(sk * LOG2E);
    rq[oidx] = f2bf(sq);
  }
}

// ---------------- fr = h @ WrT (MFMA, fused cast); srl = sr*log2e; frBt ----------------
// grid (256, 2); block 256 = 4 waves; wave w -> head blockIdx.y*4+w; 16 rows/block.
__global__ __launch_bounds__(256) void k_proj_fr(
    const float* __restrict__ h, const unsigned short* __restrict__ WrT,
    const float* __restrict__ ar,
    unsigned short* __restrict__ frBt, float* __restrict__ sr) {
  const int tid = threadIdx.x;
  const int w = tid >> 6, lane = tid & 63;
  const int c = lane & 15, g = lane >> 4;
  const int rowbase = blockIdx.x * 16;
  const int hh = blockIdx.y * 4 + w;

  f32x4 acc[4];
#pragma unroll
  for (int i = 0; i < 4; ++i) acc[i] = (f32x4){0.f, 0.f, 0.f, 0.f};

#pragma unroll 4
  for (int kt = 0; kt < 512; kt += 32) {
    const float* hp = &h[(rowbase + c) * 512 + kt + 8 * g];
    f32x4 h0 = *reinterpret_cast<const f32x4*>(hp);
    f32x4 h1 = *reinterpret_cast<const f32x4*>(hp + 4);
    u32x4 aw;
    aw[0] = pack2(h0[0], h0[1]);
    aw[1] = pack2(h0[2], h0[3]);
    aw[2] = pack2(h1[0], h1[1]);
    aw[3] = pack2(h1[2], h1[3]);
    short8 a = __builtin_bit_cast(short8, aw);
#pragma unroll
    for (int ht = 0; ht < 4; ++ht) {
      short8 bv = *reinterpret_cast<const short8*>(
          &WrT[(hh * 64 + ht * 16 + c) * 512 + kt + 8 * g]);
      acc[ht] = __builtin_amdgcn_mfma_f32_16x16x32_bf16(a, bv, acc[ht], 0, 0, 0);
    }
  }

  const int b = rowbase >> 11;
  const int bh = b * 8 + hh;
  const int nloc = rowbase & 2047;
  const int jb = nloc >> 4;  // 16-row block index

  float arv[4];
#pragma unroll
  for (int ht = 0; ht < 4; ++ht) arv[ht] = ar[ht * 16 + c];

  float ps[4];
#pragma unroll
  for (int r = 0; r < 4; ++r) {
    float s = 0.f;
#pragma unroll
    for (int ht = 0; ht < 4; ++ht) {
      float v = acc[ht][r];
      float lv = v >= 0.f ? v : 0.01f * v;
      s += lv * arv[ht];
    }
    ps[r] = s;
  }
#pragma unroll
  for (int msk = 1; msk < 16; msk <<= 1)
#pragma unroll
    for (int r = 0; r < 4; ++r) ps[r] += __shfl_xor(ps[r], msk);
  if (c == 0) {
#pragma unroll
    for (int r = 0; r < 4; ++r) sr[bh * N_ + nloc + 4 * g + r] = ps[r] * LOG2E;
  }
  // frBt[bh][jb(128)][hd(64)][jloc(16)] bf16: A-fragment layout for PV (fr^T)
#pragma unroll
  for (int ht = 0; ht < 4; ++ht) {
    int hd = ht * 16 + c;
    u32x2 ov;
    ov[0] = pack2(acc[ht][0], acc[ht][1]);
    ov[1] = pack2(acc[ht][2], acc[ht][3]);
    *reinterpret_cast<u32x2*>(
        &frBt[(((size_t)bh * 128 + jb) * 64 + hd) * 16 + 4 * g]) = ov;
  }
}

// ---------------- flash attention: LDS-staged fr, exp2 domain, bias in MFMA C ----
// grid (8, 16, 4); block 512 = 8 waves; each block = one (bh, z), stages 64KB fr quarter.
__global__ __launch_bounds__(512, 4) void k_attn(
    const unsigned short* __restrict__ rk, const unsigned short* __restrict__ rq,
    const float* __restrict__ sr, const unsigned short* __restrict__ frBt,
    unsigned short* __restrict__ O0, unsigned short* __restrict__ O1,
    unsigned short* __restrict__ O2, unsigned short* __restrict__ O3,
    float* __restrict__ lbuf) {
  __shared__ unsigned short fr_lds[32 * 64 * 16];  // 64 KB: [jb16_loc][hd][j16]
  const int tid = threadIdx.x;
  const int wave = tid >> 6, lane = tid & 63;
  const int c5 = lane & 31, hi = lane >> 5;
  const int bh = blockIdx.y, b = bh >> 3, hh = bh & 7;
  const int z = blockIdx.z;
  const int qbase = blockIdx.x * 256 + wave * 32;

  // ---- stage fr z-quarter: 32768 elems, 4096 16B-vectors, 8 per thread
  {
    const u32x4* src = reinterpret_cast<const u32x4*>(
        frBt + (((size_t)bh * 128 + z * 32) * 64) * 16);
    u32x4* dst = reinterpret_cast<u32x4*>(fr_lds);
#pragma unroll
    for (int i = 0; i < 8; ++i) dst[tid + i * 512] = src[tid + i * 512];
  }

  // B-fragment: rk rows (pre-scaled by log2e) for this wave's 32 queries
  const short8 brk =
      *reinterpret_cast<const short8*>(&rk[(bh * N_ + qbase + c5) * 16 + 8 * hi]);

  f32x16 Oa = {0.f, 0.f, 0.f, 0.f, 0.f, 0.f, 0.f, 0.f,
               0.f, 0.f, 0.f, 0.f, 0.f, 0.f, 0.f, 0.f};
  f32x16 Ob = Oa;
  f32x4 lacc = {0.f, 0.f, 0.f, 0.f};
  const float* sr_bh = sr + bh * N_;  // pre-scaled by log2e
  const unsigned short* rq_bh = rq + (size_t)bh * N_ * 16;

  __syncthreads();

#pragma unroll 2
  for (int t16 = 0; t16 < 16; ++t16) {
    const int jl = t16 * 32;             // j local to the z-quarter
    const int jg = z * 512 + jl;         // global j
    // QK: S^T[j(32) x q(32)], K=16; C-in carries the srl bias (row-placed)
    short8 a = *reinterpret_cast<const short8*>(&rq_bh[(jg + c5) * 16 + 8 * hi]);
    f32x4 sa = *reinterpret_cast<const f32x4*>(&sr_bh[jg + 4 * hi]);
    f32x4 sb = *reinterpret_cast<const f32x4*>(&sr_bh[jg + 8 + 4 * hi]);
    f32x4 sc = *reinterpret_cast<const f32x4*>(&sr_bh[jg + 16 + 4 * hi]);
    f32x4 sd = *reinterpret_cast<const f32x4*>(&sr_bh[jg + 24 + 4 * hi]);
    f32x16 S;
#pragma unroll
    for (int r = 0; r < 4; ++r) {
      S[r] = sa[r];
      S[4 + r] = sb[r];
      S[8 + r] = sc[r];
      S[12 + r] = sd[r];
    }
    S = __builtin_amdgcn_mfma_f32_32x32x16_bf16(a, brk, S, 0, 0, 0);
    // P = 2^S (scores already in exp2 domain); accumulate l vector-wise
#pragma unroll
    for (int r = 0; r < 16; ++r) S[r] = exp2f(S[r]);
    f32x4 s0 = {S[0], S[1], S[2], S[3]};
    f32x4 s1 = {S[4], S[5], S[6], S[7]};
    f32x4 s2 = {S[8], S[9], S[10], S[11]};
    f32x4 s3 = {S[12], S[13], S[14], S[15]};
    lacc += (s0 + s1) + (s2 + s3);
    // pack P (C/D layout) -> PV B-fragments via permlane32_swap
    int A1 = (int)pack2(S[0], S[1]), B1 = (int)pack2(S[2], S[3]);
    int C1 = (int)pack2(S[4], S[5]), D1 = (int)pack2(S[6], S[7]);
    i32x2 r0 = __builtin_amdgcn_permlane32_swap(A1, C1, false, false);
    i32x2 r1 = __builtin_amdgcn_permlane32_swap(B1, D1, false, false);
    int A2 = (int)pack2(S[8], S[9]), B2 = (int)pack2(S[10], S[11]);
    int C2 = (int)pack2(S[12], S[13]), D2 = (int)pack2(S[14], S[15]);
    i32x2 r2 = __builtin_amdgcn_permlane32_swap(A2, C2, false, false);
    i32x2 r3 = __builtin_amdgcn_permlane32_swap(B2, D2, false, false);
    u32x4 f1, f2;
    f1[0] = (unsigned)r0[0]; f1[1] = (unsigned)r1[0];
    f1[2] = (unsigned)r0[1]; f1[3] = (unsigned)r1[1];
    f2[0] = (unsigned)r2[0]; f2[1] = (unsigned)r3[0];
    f2[2] = (unsigned)r2[1]; f2[3] = (unsigned)r3[1];
    short8 pb1 = __builtin_bit_cast(short8, f1);
    short8 pb2 = __builtin_bit_cast(short8, f2);
    // PV from LDS: O^T[hd x q] += fr^T[hd x j] * P^T[j x q]
    const unsigned short* fp0 = fr_lds + ((jl >> 4) * 64) * 16 + 8 * hi;
    const unsigned short* fp1 = fp0 + 64 * 16;
    __builtin_amdgcn_s_setprio(1);
    short8 av;
    av = *reinterpret_cast<const short8*>(fp0 + c5 * 16);
    Oa = __builtin_amdgcn_mfma_f32_32x32x16_bf16(av, pb1, Oa, 0, 0, 0);
    av = *reinterpret_cast<const short8*>(fp0 + (32 + c5) * 16);
    Ob = __builtin_amdgcn_mfma_f32_32x32x16_bf16(av, pb1, Ob, 0, 0, 0);
    av = *reinterpret_cast<const short8*>(fp1 + c5 * 16);
    Oa = __builtin_amdgcn_mfma_f32_32x32x16_bf16(av, pb2, Oa, 0, 0, 0);
    av = *reinterpret_cast<const short8*>(fp1 + (32 + c5) * 16);
    Ob = __builtin_amdgcn_mfma_f32_32x32x16_bf16(av, pb2, Ob, 0, 0, 0);
    __builtin_amdgcn_s_setprio(0);
  }
  // epilogue
  float l = (lacc[0] + lacc[1]) + (lacc[2] + lacc[3]);
  l += __shfl_xor(l, 32);
  if (hi == 0) lbuf[(z * 16 + bh) * N_ + qbase + c5] = l;
  unsigned short* Oz = (z == 0) ? O0 : (z == 1) ? O1 : (z == 2) ? O2 : O3;
  unsigned int* orow = reinterpret_cast<unsigned int*>(
      &Oz[((size_t)(b * N_ + qbase + c5)) * 512 + hh * 64]);
#pragma unroll
  for (int r = 0; r < 16; r += 2) {
    const int hd = (r & 3) + 8 * (r >> 2) + 4 * hi;
    orow[hd >> 1] = pack2(Oa[r], Oa[r + 1]);
    orow[(32 + hd) >> 1] = pack2(Ob[r], Ob[r + 1]);
  }
}

// ---------------- fused: combine 4 KV-splits + x = ctx @ WfT + h + LayerNorm ----------------
// grid 256 blocks of 16 rows; 8 waves, wave w = col-tile w.
__global__ __launch_bounds__(512) void k_final(
    const unsigned short* __restrict__ O0, const unsigned short* __restrict__ O1,
    const unsigned short* __restrict__ O2, const unsigned short* __restrict__ O3,
    const float* __restrict__ lbuf, const unsigned short* __restrict__ WfT,
    const float* __restrict__ h, const float* __restrict__ gamma,
    const float* __restrict__ beta, float* __restrict__ out) {
  __shared__ unsigned short ctx_lds[16][520];  // row stride 1040B (65x16B)
  __shared__ float red[2][16][9];
  __shared__ float mur[16], rsr[16];
  const int tid = threadIdx.x;
  const int w = tid >> 6, lane = tid & 63;
  const int c = lane & 15, g = lane >> 4;
  const int rowbase = blockIdx.x * 16;

  // ---- combine O0..O3 into ctx_lds (bf16)
  {
    const int row = tid >> 5;            // 0..15
    const int b = (rowbase + row) >> 11, n = (rowbase + row) & 2047;
#pragma unroll
    for (int i = 0; i < 2; ++i) {
      const int col = ((tid & 31) + i * 32) * 8;  // 0..504
      const int bh = b * 8 + (col >> 6);
      const float denom = lbuf[bh * N_ + n] + lbuf[(16 + bh) * N_ + n] +
                          lbuf[(32 + bh) * N_ + n] + lbuf[(48 + bh) * N_ + n];
      const float inv = 1.f / denom;
      const size_t off = (size_t)(rowbase + row) * 512 + col;
      u32x4 v0 = *reinterpret_cast<const u32x4*>(&O0[off]);
      u32x4 v1 = *reinterpret_cast<const u32x4*>(&O1[off]);
      u32x4 v2 = *reinterpret_cast<const u32x4*>(&O2[off]);
      u32x4 v3 = *reinterpret_cast<const u32x4*>(&O3[off]);
      u32x4 ov;
#pragma unroll
      for (int j = 0; j < 4; ++j) {
        float lo = bf2f((unsigned short)(v0[j] & 0xffff)) + bf2f((unsigned short)(v1[j] & 0xffff)) +
                   bf2f((unsigned short)(v2[j] & 0xffff)) + bf2f((unsigned short)(v3[j] & 0xffff));
        float hi = bf2f((unsigned short)(v0[j] >> 16)) + bf2f((unsigned short)(v1[j] >> 16)) +
                   bf2f((unsigned short)(v2[j] >> 16)) + bf2f((unsigned short)(v3[j] >> 16));
        ov[j] = pack2(lo * inv, hi * inv);
      }
      *reinterpret_cast<u32x4*>(&ctx_lds[row][col]) = ov;
    }
  }
  __syncthreads();

  f32x4 acc[4];
#pragma unroll
  for (int i = 0; i < 4; ++i) acc[i] = (f32x4){0.f, 0.f, 0.f, 0.f};

#pragma unroll 4
  for (int kt = 0; kt < 512; kt += 32) {
    short8 a = *reinterpret_cast<const short8*>(&ctx_lds[c][kt + 8 * g]);
#pragma unroll
    for (int ht = 0; ht < 4; ++ht) {
      short8 bv = *reinterpret_cast<const short8*>(
          &WfT[(w * 64 + ht * 16 + c) * 512 + kt + 8 * g]);
      acc[ht] = __builtin_amdgcn_mfma_f32_16x16x32_bf16(a, bv, acc[ht], 0, 0, 0);
    }
  }
  // x = fh + h ; per-row stats
  float x[4][4];
  float px[4], pxx[4];
#pragma unroll
  for (int r = 0; r < 4; ++r) { px[r] = 0.f; pxx[r] = 0.f; }
#pragma unroll
  for (int ht = 0; ht < 4; ++ht)
#pragma unroll
    for (int r = 0; r < 4; ++r) {
      float v = acc[ht][r] + h[(rowbase + 4 * g + r) * 512 + w * 64 + ht * 16 + c];
      x[ht][r] = v;
      px[r] += v;
      pxx[r] += v * v;
    }
#pragma unroll
  for (int msk = 1; msk < 16; msk <<= 1)
#pragma unroll
    for (int r = 0; r < 4; ++r) {
      px[r] += __shfl_xor(px[r], msk);
      pxx[r] += __shfl_xor(pxx[r], msk);
    }
  if (c == 0) {
#pragma unroll
    for (int r = 0; r < 4; ++r) {
      red[0][4 * g + r][w] = px[r];
      red[1][4 * g + r][w] = pxx[r];
    }
  }
  __syncthreads();
  if (tid < 16) {
    float s = 0.f, sq = 0.f;
#pragma unroll
    for (int wv = 0; wv < 8; ++wv) { s += red[0][tid][wv]; sq += red[1][tid][wv]; }
    float mu = s * (1.f / 512.f);
    float var = sq * (1.f / 512.f) - mu * mu;
    mur[tid] = mu;
    rsr[tid] = rsqrtf(var + 1e-5f);
  }
  __syncthreads();
#pragma unroll
  for (int ht = 0; ht < 4; ++ht)
#pragma unroll
    for (int r = 0; r < 4; ++r) {
      const int col = w * 64 + ht * 16 + c;
      const float mu = mur[4 * g + r], rs = rsr[4 * g + r];
      out[(rowbase + 4 * g + r) * 512 + col] =
          (x[ht][r] - mu) * rs * gamma[col] + beta[col];
    }
}

extern "C" void kernel_launch(void* const* d_in, const int* in_sizes, int n_in,
                              void* d_out, int out_size, void* d_ws, size_t ws_size,
                              hipStream_t stream) {
  const float* h     = (const float*)d_in[0];
  const float* rh    = (const float*)d_in[1];
  // d_in[2] = Wl, d_in[4] = al: dead (softmax shift-invariance along j)
  const float* Wr    = (const float*)d_in[3];
  const float* ar    = (const float*)d_in[5];
  const float* Wrs   = (const float*)d_in[6];
  const float* Wrt   = (const float*)d_in[7];
  const float* Wf    = (const float*)d_in[8];
  const float* gamma = (const float*)d_in[9];
  const float* beta  = (const float*)d_in[10];

  const size_t MB = 1ull << 20;
  char* ws = (char*)d_ws;
  unsigned short* frBt = (unsigned short*)(ws);                          // 4 MB
  unsigned short* rk   = (unsigned short*)(ws + 4 * MB);                 // 1 MB
  unsigned short* rq   = (unsigned short*)(ws + 5 * MB);                 // 1 MB
  float*          sr   = (float*)(ws + 6 * MB);                          // 128 KB
  float*          lbuf = (float*)(ws + 6 * MB + 256 * 1024);             // 512 KB
  unsigned short* WrT  = (unsigned short*)(ws + 6 * MB + 768 * 1024);    // 512 KB
  unsigned short* WfT  = (unsigned short*)(ws + 7 * MB + 256 * 1024);    // 512 KB
  unsigned short* O0   = (unsigned short*)(ws + 7 * MB + 768 * 1024);    // 4 MB
  unsigned short* O1   = (unsigned short*)(ws + 11 * MB + 768 * 1024);   // 4 MB (15.75 MB)
  unsigned short* O2   = (unsigned short*)d_out;                         // 4 MB (scratch)
  unsigned short* O3   = (unsigned short*)((char*)d_out + 4 * MB);       // 4 MB (scratch)

  hipLaunchKernelGGL(k_prep, dim3(2560), dim3(256), 0, stream,
                     Wr, Wf, rh, Wrs, Wrt, WrT, WfT, rk, rq);
  hipLaunchKernelGGL(k_proj_fr, dim3(256, 2), dim3(256), 0, stream, h, WrT, ar, frBt, sr);
  hipLaunchKernelGGL(k_attn, dim3(8, 16, 4), dim3(512), 0, stream, rk, rq, sr, frBt,
                     O0, O1, O2, O3, lbuf);
  hipLaunchKernelGGL(k_final, dim3(256), dim3(512), 0, stream, O0, O1, O2, O3, lbuf,
                     WfT, h, gamma, beta, (float*)d_out);
}